// Round 2
// baseline (1201.843 us; speedup 1.0000x reference)
//
#include <hip/hip_runtime.h>
#include <cstdint>
#include <cstddef>

typedef unsigned short u16;
typedef __attribute__((ext_vector_type(8))) short short8;
typedef __attribute__((ext_vector_type(4))) float f32x4;

// ---------- bf16 helpers (OCP bf16 = top 16 bits of fp32, RNE) ----------
__device__ __forceinline__ float bf2f(u16 u) {
  union { uint32_t u; float f; } x; x.u = ((uint32_t)u) << 16; return x.f;
}
__device__ __forceinline__ u16 f2bf(float f) {
  union { float f; uint32_t u; } x; x.f = f;
  uint32_t r = x.u + 0x7FFFu + ((x.u >> 16) & 1u);
  return (u16)(r >> 16);
}
__device__ __forceinline__ float silu_f(float x) { return x / (1.f + __expf(-x)); }

// ---------- weight fp32 -> bf16 convert with zero padding + row offset ----------
__global__ void cvt_pad_kernel(const float* __restrict__ in, u16* __restrict__ out,
                               int cols_out, int rows_in, int cols_in, int row_off, int total) {
  int i = blockIdx.x * 256 + threadIdx.x;
  if (i >= total) return;
  int r = i / cols_out, ci = i - r * cols_out;
  float v = 0.f;
  if (r < rows_in && ci < cols_in) v = in[(size_t)(r + row_off) * cols_in + ci];
  out[i] = f2bf(v);
}

// ---------- mods = silu(c) @ ada_w.T + ada_b   (B=2, 9216 outputs each) ----------
__global__ void mods_kernel(const float* __restrict__ c, const float* __restrict__ ada_w,
                            const float* __restrict__ ada_b, float* __restrict__ mods) {
  int j = blockIdx.x * 4 + (threadIdx.x >> 6);
  int lane = threadIdx.x & 63;
  float a0 = 0.f, a1 = 0.f;
  for (int k = lane; k < 1024; k += 64) {
    float w = ada_w[(size_t)j * 1024 + k];
    a0 += silu_f(c[k]) * w;
    a1 += silu_f(c[1024 + k]) * w;
  }
  #pragma unroll
  for (int off = 32; off > 0; off >>= 1) { a0 += __shfl_down(a0, off); a1 += __shfl_down(a1, off); }
  if (lane == 0) {
    float bb = ada_b[j];
    mods[j] = a0 + bb;
    mods[9216 + j] = a1 + bb;
  }
}

// ---------- rmsnorm(D=1024) * (1+sc) + sh  -> bf16 rows; optional (t,l) transpose ----------
__global__ __launch_bounds__(256) void norm_mod_kernel(
    const float* __restrict__ X, u16* __restrict__ Y,
    const float* __restrict__ nw, const float* __restrict__ mods,
    int sh_idx, int transpose) {
  int row = blockIdx.x;           // output row
  int b = row >> 12;
  int in_row;
  if (transpose) { int rem = row & 4095; int l = rem >> 4, t = rem & 15; in_row = (b << 12) + (t << 8) + l; }
  else in_row = row;
  int tid = threadIdx.x;
  float4 v = ((const float4*)(X + (size_t)in_row * 1024))[tid];
  float ss = v.x * v.x + v.y * v.y + v.z * v.z + v.w * v.w;
  #pragma unroll
  for (int off = 32; off > 0; off >>= 1) ss += __shfl_down(ss, off);
  __shared__ float red[4];
  if ((tid & 63) == 0) red[tid >> 6] = ss;
  __syncthreads();
  float rms = rsqrtf((red[0] + red[1] + red[2] + red[3]) * (1.f / 1024.f) + 1e-6f);
  const float* mb = mods + (size_t)b * 9216 + (size_t)sh_idx * 1024;
  float4 sh = ((const float4*)mb)[tid];
  float4 sc = ((const float4*)(mb + 1024))[tid];
  float4 w  = ((const float4*)nw)[tid];
  ushort4 o;
  o.x = f2bf(v.x * rms * w.x * (1.f + sc.x) + sh.x);
  o.y = f2bf(v.y * rms * w.y * (1.f + sc.y) + sh.y);
  o.z = f2bf(v.z * rms * w.z * (1.f + sc.z) + sh.z);
  o.w = f2bf(v.w * rms * w.w * (1.f + sc.w) + sh.w);
  ((ushort4*)(Y + (size_t)row * 1024))[tid] = o;
}

// ---------- bf16 MFMA GEMM: C[M,N] = A[M,K] @ W[N,K]^T + bias ----------
// 128x128 tile, 256 threads (4 waves), each wave 64x64 = 4x4 of 16x16x32 MFMA.
#define LDSP 40   // padded LDS row stride in bf16 elems (32 data + 8 pad)
template<int STORE_BF16>
__global__ __launch_bounds__(256) void gemm_bt(
    const u16* __restrict__ A, const u16* __restrict__ W,
    const float* __restrict__ bias, void* __restrict__ Cv,
    int M, int N, int K, int ldc) {
  __shared__ u16 As[128 * LDSP];
  __shared__ u16 Bs[128 * LDSP];
  int tid = threadIdx.x;
  int wid = tid >> 6, lane = tid & 63;
  int quad = lane >> 4, r = lane & 15;
  int m0 = blockIdx.y * 128, n0 = blockIdx.x * 128;
  int wm = (wid >> 1) * 64, wn = (wid & 1) * 64;

  f32x4 zero = {0.f, 0.f, 0.f, 0.f};
  f32x4 acc[4][4];
  #pragma unroll
  for (int i = 0; i < 4; i++)
    #pragma unroll
    for (int j = 0; j < 4; j++) acc[i][j] = zero;

  for (int k0 = 0; k0 < K; k0 += 32) {
    #pragma unroll
    for (int i = 0; i < 2; i++) {
      int idx = tid + i * 256;
      int row = idx >> 2, cb = idx & 3;
      *(uint4*)(As + row * LDSP + cb * 8) = *(const uint4*)(A + (size_t)(m0 + row) * K + k0 + cb * 8);
      *(uint4*)(Bs + row * LDSP + cb * 8) = *(const uint4*)(W + (size_t)(n0 + row) * K + k0 + cb * 8);
    }
    __syncthreads();
    short8 afr[4], bfr[4];
    #pragma unroll
    for (int i = 0; i < 4; i++) afr[i] = *(const short8*)(As + (wm + i * 16 + r) * LDSP + quad * 8);
    #pragma unroll
    for (int j = 0; j < 4; j++) bfr[j] = *(const short8*)(Bs + (wn + j * 16 + r) * LDSP + quad * 8);
    #pragma unroll
    for (int i = 0; i < 4; i++)
      #pragma unroll
      for (int j = 0; j < 4; j++)
        acc[i][j] = __builtin_amdgcn_mfma_f32_16x16x32_bf16(afr[i], bfr[j], acc[i][j], 0, 0, 0);
    __syncthreads();
  }

  float* Cf = (float*)Cv;
  u16* Ch = (u16*)Cv;
  #pragma unroll
  for (int i = 0; i < 4; i++) {
    #pragma unroll
    for (int j = 0; j < 4; j++) {
      int col = n0 + wn + j * 16 + r;
      if (col < N) {
        float bv = bias[col];
        #pragma unroll
        for (int rr = 0; rr < 4; rr++) {
          int row = m0 + wm + i * 16 + quad * 4 + rr;
          float vv = acc[i][j][rr] + bv;
          if (STORE_BF16) Ch[(size_t)row * ldc + col] = f2bf(vv);
          else            Cf[(size_t)row * ldc + col] = vv;
        }
      }
    }
  }
}

// ---------- fused w12 GEMM + SwiGLU: Hb[m, n] = silu(A@W1^T + b1) * (A@W2^T + b2) ----------
// M=8192, Npad=2816 (HFF=2730 zero-padded), K=1024, out bf16 ldc=2816.
__global__ __launch_bounds__(256) void gemm_w12_swiglu(
    const u16* __restrict__ A, const u16* __restrict__ W1, const u16* __restrict__ W2,
    const float* __restrict__ bias, u16* __restrict__ Hb) {
  __shared__ u16 As[128 * LDSP];
  __shared__ u16 B1s[128 * LDSP];
  __shared__ u16 B2s[128 * LDSP];
  int tid = threadIdx.x;
  int wid = tid >> 6, lane = tid & 63;
  int quad = lane >> 4, r = lane & 15;
  int m0 = blockIdx.y * 128, n0 = blockIdx.x * 128;
  int wm = (wid >> 1) * 64, wn = (wid & 1) * 64;

  f32x4 zero = {0.f, 0.f, 0.f, 0.f};
  f32x4 acc1[4][4], acc2[4][4];
  #pragma unroll
  for (int i = 0; i < 4; i++)
    #pragma unroll
    for (int j = 0; j < 4; j++) { acc1[i][j] = zero; acc2[i][j] = zero; }

  for (int k0 = 0; k0 < 1024; k0 += 32) {
    #pragma unroll
    for (int i = 0; i < 2; i++) {
      int idx = tid + i * 256;
      int row = idx >> 2, cb = idx & 3;
      *(uint4*)(As  + row * LDSP + cb * 8) = *(const uint4*)(A  + (size_t)(m0 + row) * 1024 + k0 + cb * 8);
      *(uint4*)(B1s + row * LDSP + cb * 8) = *(const uint4*)(W1 + (size_t)(n0 + row) * 1024 + k0 + cb * 8);
      *(uint4*)(B2s + row * LDSP + cb * 8) = *(const uint4*)(W2 + (size_t)(n0 + row) * 1024 + k0 + cb * 8);
    }
    __syncthreads();
    short8 afr[4], b1fr[4], b2fr[4];
    #pragma unroll
    for (int i = 0; i < 4; i++) afr[i]  = *(const short8*)(As  + (wm + i * 16 + r) * LDSP + quad * 8);
    #pragma unroll
    for (int j = 0; j < 4; j++) b1fr[j] = *(const short8*)(B1s + (wn + j * 16 + r) * LDSP + quad * 8);
    #pragma unroll
    for (int j = 0; j < 4; j++) b2fr[j] = *(const short8*)(B2s + (wn + j * 16 + r) * LDSP + quad * 8);
    #pragma unroll
    for (int i = 0; i < 4; i++)
      #pragma unroll
      for (int j = 0; j < 4; j++) {
        acc1[i][j] = __builtin_amdgcn_mfma_f32_16x16x32_bf16(afr[i], b1fr[j], acc1[i][j], 0, 0, 0);
        acc2[i][j] = __builtin_amdgcn_mfma_f32_16x16x32_bf16(afr[i], b2fr[j], acc2[i][j], 0, 0, 0);
      }
    __syncthreads();
  }

  #pragma unroll
  for (int i = 0; i < 4; i++) {
    #pragma unroll
    for (int j = 0; j < 4; j++) {
      int col = n0 + wn + j * 16 + r;
      float b1 = (col < 2730) ? bias[col] : 0.f;
      float b2 = (col < 2730) ? bias[2730 + col] : 0.f;
      #pragma unroll
      for (int rr = 0; rr < 4; rr++) {
        int row = m0 + wm + i * 16 + quad * 4 + rr;
        float h1 = acc1[i][j][rr] + b1;
        float h2 = acc2[i][j][rr] + b2;
        Hb[(size_t)row * 2816 + col] = f2bf(silu_f(h1) * h2);
      }
    }
  }
}

// ---------- spatial attention: seq=256, one block per (head, batch-group), thread = q row ----------
__global__ __launch_bounds__(256) void attn_s_kernel(
    const u16* __restrict__ QKV,   // (32*256) x 3072 bf16: [q|k|v], head-major 64 each
    const float* __restrict__ qn_w, const float* __restrict__ kn_w,
    const float* __restrict__ cosT, const float* __restrict__ sinT,  // 256 x 64
    u16* __restrict__ AO) {
  __shared__ u16 kb[256 * 64];
  __shared__ u16 vb[256 * 64];
  int h = blockIdx.x, s = blockIdx.y;
  int t = threadIdx.x;
  size_t rowbase = ((size_t)(s * 256 + t)) * 3072;
  {
    const u16* kr = QKV + rowbase + 1024 + h * 64;
    float xk[64]; float ss = 0.f;
    #pragma unroll
    for (int d = 0; d < 64; d++) { xk[d] = bf2f(kr[d]); ss += xk[d] * xk[d]; }
    float rms = rsqrtf(ss * (1.f / 64.f) + 1e-6f);
    #pragma unroll
    for (int d = 0; d < 64; d++) xk[d] *= rms * kn_w[d];
    #pragma unroll
    for (int d = 0; d < 32; d++) {
      float a = xk[d], bb = xk[d + 32];
      kb[t * 64 + d]      = f2bf(a * cosT[t * 64 + d]       - bb * sinT[t * 64 + d]);
      kb[t * 64 + 32 + d] = f2bf(bb * cosT[t * 64 + 32 + d] + a * sinT[t * 64 + 32 + d]);
    }
    const u16* vr = QKV + rowbase + 2048 + h * 64;
    #pragma unroll
    for (int d = 0; d < 64; d++) vb[t * 64 + d] = vr[d];
  }
  float q[64];
  {
    const u16* qr = QKV + rowbase + h * 64;
    float ss = 0.f;
    #pragma unroll
    for (int d = 0; d < 64; d++) { q[d] = bf2f(qr[d]); ss += q[d] * q[d]; }
    float rms = rsqrtf(ss * (1.f / 64.f) + 1e-6f);
    #pragma unroll
    for (int d = 0; d < 64; d++) q[d] *= rms * qn_w[d];
    #pragma unroll
    for (int d = 0; d < 32; d++) {
      float a = q[d], bb = q[d + 32];
      q[d]      = a * cosT[t * 64 + d]       - bb * sinT[t * 64 + d];
      q[d + 32] = bb * cosT[t * 64 + 32 + d] + a * sinT[t * 64 + 32 + d];
    }
  }
  __syncthreads();
  float m = -1e30f, ssum = 0.f;
  float o[64];
  #pragma unroll
  for (int d = 0; d < 64; d++) o[d] = 0.f;
  for (int j = 0; j < 256; j++) {
    float sc = 0.f;
    const short8* krow = (const short8*)(kb + j * 64);
    #pragma unroll
    for (int vv = 0; vv < 8; vv++) {
      short8 kk = krow[vv];
      #pragma unroll
      for (int e = 0; e < 8; e++) sc += q[vv * 8 + e] * bf2f((u16)kk[e]);
    }
    sc *= 0.125f;
    float mn = fmaxf(m, sc);
    float alpha = __expf(m - mn);
    float p = __expf(sc - mn);
    ssum = ssum * alpha + p;
    const short8* vrow = (const short8*)(vb + j * 64);
    #pragma unroll
    for (int vv = 0; vv < 8; vv++) {
      short8 vk = vrow[vv];
      #pragma unroll
      for (int e = 0; e < 8; e++) o[vv * 8 + e] = o[vv * 8 + e] * alpha + p * bf2f((u16)vk[e]);
    }
    m = mn;
  }
  float inv = 1.f / ssum;
  u16* op = AO + ((size_t)(s * 256 + t)) * 1024 + h * 64;
  #pragma unroll
  for (int d = 0; d < 64; d++) op[d] = f2bf(o[d] * inv);
}

// ---------- temporal attention: seq=16, block per (b,l), thread = (head, t) ----------
__global__ __launch_bounds__(256) void attn_t_kernel(
    const u16* __restrict__ QKV,   // (512*16) x 3072 bf16, rows in (b,l,t) order
    const float* __restrict__ qn_w, const float* __restrict__ kn_w,
    const float* __restrict__ cosT, const float* __restrict__ sinT,  // 16 x 64
    u16* __restrict__ AO) {
  __shared__ u16 kb[256 * 64];
  __shared__ u16 vb[256 * 64];
  int bl = blockIdx.x;
  int tid = threadIdx.x;
  int h = tid >> 4, t = tid & 15;
  size_t rowbase = ((size_t)(bl * 16 + t)) * 3072;
  int slot = h * 16 + t;
  {
    const u16* kr = QKV + rowbase + 1024 + h * 64;
    float xk[64]; float ss = 0.f;
    #pragma unroll
    for (int d = 0; d < 64; d++) { xk[d] = bf2f(kr[d]); ss += xk[d] * xk[d]; }
    float rms = rsqrtf(ss * (1.f / 64.f) + 1e-6f);
    #pragma unroll
    for (int d = 0; d < 64; d++) xk[d] *= rms * kn_w[d];
    #pragma unroll
    for (int d = 0; d < 32; d++) {
      float a = xk[d], bb = xk[d + 32];
      kb[slot * 64 + d]      = f2bf(a * cosT[t * 64 + d]       - bb * sinT[t * 64 + d]);
      kb[slot * 64 + 32 + d] = f2bf(bb * cosT[t * 64 + 32 + d] + a * sinT[t * 64 + 32 + d]);
    }
    const u16* vr = QKV + rowbase + 2048 + h * 64;
    #pragma unroll
    for (int d = 0; d < 64; d++) vb[slot * 64 + d] = vr[d];
  }
  float q[64];
  {
    const u16* qr = QKV + rowbase + h * 64;
    float ss = 0.f;
    #pragma unroll
    for (int d = 0; d < 64; d++) { q[d] = bf2f(qr[d]); ss += q[d] * q[d]; }
    float rms = rsqrtf(ss * (1.f / 64.f) + 1e-6f);
    #pragma unroll
    for (int d = 0; d < 64; d++) q[d] *= rms * qn_w[d];
    #pragma unroll
    for (int d = 0; d < 32; d++) {
      float a = q[d], bb = q[d + 32];
      q[d]      = a * cosT[t * 64 + d]       - bb * sinT[t * 64 + d];
      q[d + 32] = bb * cosT[t * 64 + 32 + d] + a * sinT[t * 64 + 32 + d];
    }
  }
  __syncthreads();
  float scv[16]; float mx = -1e30f;
  #pragma unroll
  for (int j = 0; j < 16; j++) {
    float sc = 0.f;
    const short8* krow = (const short8*)(kb + (h * 16 + j) * 64);
    #pragma unroll
    for (int vv = 0; vv < 8; vv++) {
      short8 kk = krow[vv];
      #pragma unroll
      for (int e = 0; e < 8; e++) sc += q[vv * 8 + e] * bf2f((u16)kk[e]);
    }
    scv[j] = sc * 0.125f;
    mx = fmaxf(mx, scv[j]);
  }
  float ssum = 0.f;
  #pragma unroll
  for (int j = 0; j < 16; j++) { scv[j] = __expf(scv[j] - mx); ssum += scv[j]; }
  float inv = 1.f / ssum;
  float o[64];
  #pragma unroll
  for (int d = 0; d < 64; d++) o[d] = 0.f;
  #pragma unroll
  for (int j = 0; j < 16; j++) {
    const short8* vrow = (const short8*)(vb + (h * 16 + j) * 64);
    #pragma unroll
    for (int vv = 0; vv < 8; vv++) {
      short8 vk = vrow[vv];
      #pragma unroll
      for (int e = 0; e < 8; e++) o[vv * 8 + e] += scv[j] * bf2f((u16)vk[e]);
    }
  }
  u16* op = AO + ((size_t)(bl * 16 + t)) * 1024 + h * 64;
  #pragma unroll
  for (int d = 0; d < 64; d++) op[d] = f2bf(o[d] * inv);
}

// ---------- residual: out = base + g[b,d] * P (optional (b,l,t)->(b,t,l) gather of P) ----------
__global__ void resid_kernel(const float* __restrict__ base, const float* __restrict__ P,
                             const float* __restrict__ mods, int gidx,
                             float* __restrict__ out, int transpose) {
  int e = blockIdx.x * 256 + threadIdx.x;
  int row = e >> 10, d = e & 1023;
  int b = row >> 12;
  float g = mods[(size_t)b * 9216 + (size_t)gidx * 1024 + d];
  float p;
  if (transpose) {
    int rem = row & 4095; int t = rem >> 8, l = rem & 255;
    size_t mp = ((size_t)(b << 12)) + (l << 4) + t;
    p = P[(mp << 10) + d];
  } else p = P[e];
  out[e] = base[e] + g * p;
}

// =====================================================================
extern "C" void kernel_launch(void* const* d_in, const int* in_sizes, int n_in,
                              void* d_out, int out_size, void* d_ws, size_t ws_size,
                              hipStream_t stream) {
  const float* x        = (const float*)d_in[0];
  const float* c        = (const float*)d_in[1];
  const float* cos_s    = (const float*)d_in[2];
  const float* sin_s    = (const float*)d_in[3];
  const float* cos_t    = (const float*)d_in[4];
  const float* sin_t    = (const float*)d_in[5];
  const float* norm1w   = (const float*)d_in[6];
  const float* norm2w   = (const float*)d_in[7];
  const float* norm3w   = (const float*)d_in[8];
  const float* qkv_s_w  = (const float*)d_in[9];
  const float* qkv_s_b  = (const float*)d_in[10];
  const float* qn_s_w   = (const float*)d_in[11];
  const float* kn_s_w   = (const float*)d_in[12];
  const float* proj_s_w = (const float*)d_in[13];
  const float* proj_s_b = (const float*)d_in[14];
  const float* qkv_t_w  = (const float*)d_in[15];
  const float* qkv_t_b  = (const float*)d_in[16];
  const float* qn_t_w   = (const float*)d_in[17];
  const float* kn_t_w   = (const float*)d_in[18];
  const float* proj_t_w = (const float*)d_in[19];
  const float* proj_t_b = (const float*)d_in[20];
  const float* w12_w    = (const float*)d_in[21];
  const float* w12_b    = (const float*)d_in[22];
  const float* w3_w     = (const float*)d_in[23];
  const float* w3_b     = (const float*)d_in[24];
  const float* ada_w    = (const float*)d_in[25];
  const float* ada_b    = (const float*)d_in[26];
  float* out = (float*)d_out;

  // ---- workspace layout: ~112.6 MiB total (was 257 MiB -> silent bail) ----
  char* wsp = (char*)d_ws;
  size_t off = 0;
  auto alloc = [&](size_t bytes) { size_t p = off; off += (bytes + 255) & ~(size_t)255; return p; };
  float* modsb = (float*)(wsp + alloc(2 * 9216 * 4));
  u16*   BIG   = (u16*)  (wsp + alloc((size_t)8192 * 3072 * 2));  // QKV (st1,2) / Hb 8192x2816 (st3)
  char*  XnP   = (char*) (wsp + alloc((size_t)8192 * 1024 * 4));  // Xn bf16 16.8MB  <->  P fp32 33.5MB
  u16*   AO    = (u16*)  (wsp + alloc((size_t)8192 * 1024 * 2));
  u16*   Wq    = (u16*)  (wsp + alloc((size_t)3072 * 1024 * 2));  // qkv weights (stage 1 then 2) / W1p (st3)
  u16*   Wp    = (u16*)  (wsp + alloc((size_t)2816 * 1024 * 2));  // proj weights / W2p tail (st3)
  u16*   W3b   = (u16*)  (wsp + alloc((size_t)1024 * 2816 * 2));
  // stage-3 aliases: W1p/W2p (2816x1024 each = 5,767,168 B) fit in Wq(6,291,456)+Wp(5,767,168)
  u16* W1p = Wq;
  u16* W2p = Wp;
  u16* Xn  = (u16*)XnP;
  float* P = (float*)XnP;
  float* Xcur = out;   // residual stream lives in d_out (fully overwritten before each read)

  dim3 blk(256);
  int tot;
  // adaLN modulations
  mods_kernel<<<2304, blk, 0, stream>>>(c, ada_w, ada_b, modsb);

  // ---- stage 1: spatial attention ----
  tot = 3072 * 1024; cvt_pad_kernel<<<(tot + 255) / 256, blk, 0, stream>>>(qkv_s_w, Wq, 1024, 3072, 1024, 0, tot);
  tot = 1024 * 1024; cvt_pad_kernel<<<(tot + 255) / 256, blk, 0, stream>>>(proj_s_w, Wp, 1024, 1024, 1024, 0, tot);
  norm_mod_kernel<<<8192, blk, 0, stream>>>(x, Xn, norm1w, modsb, 0, 0);
  gemm_bt<1><<<dim3(24, 64), blk, 0, stream>>>(Xn, Wq, qkv_s_b, BIG, 8192, 3072, 1024, 3072);
  attn_s_kernel<<<dim3(16, 32), blk, 0, stream>>>(BIG, qn_s_w, kn_s_w, cos_s, sin_s, AO);
  gemm_bt<0><<<dim3(8, 64), blk, 0, stream>>>(AO, Wp, proj_s_b, P, 8192, 1024, 1024, 1024);
  resid_kernel<<<32768, blk, 0, stream>>>(x, P, modsb, 2, Xcur, 0);

  // ---- stage 2: temporal attention (rows in (b,l,t) order) ----
  tot = 3072 * 1024; cvt_pad_kernel<<<(tot + 255) / 256, blk, 0, stream>>>(qkv_t_w, Wq, 1024, 3072, 1024, 0, tot);
  tot = 1024 * 1024; cvt_pad_kernel<<<(tot + 255) / 256, blk, 0, stream>>>(proj_t_w, Wp, 1024, 1024, 1024, 0, tot);
  norm_mod_kernel<<<8192, blk, 0, stream>>>(Xcur, Xn, norm2w, modsb, 3, 1);
  gemm_bt<1><<<dim3(24, 64), blk, 0, stream>>>(Xn, Wq, qkv_t_b, BIG, 8192, 3072, 1024, 3072);
  attn_t_kernel<<<512, blk, 0, stream>>>(BIG, qn_t_w, kn_t_w, cos_t, sin_t, AO);
  gemm_bt<0><<<dim3(8, 64), blk, 0, stream>>>(AO, Wp, proj_t_b, P, 8192, 1024, 1024, 1024);
  resid_kernel<<<32768, blk, 0, stream>>>(Xcur, P, modsb, 5, Xcur, 1);

  // ---- stage 3: SwiGLU MLP (HFF 2730 padded to 2816 = 22*128) ----
  tot = 2816 * 1024; cvt_pad_kernel<<<(tot + 255) / 256, blk, 0, stream>>>(w12_w, W1p, 1024, 2730, 1024, 0, tot);
  tot = 2816 * 1024; cvt_pad_kernel<<<(tot + 255) / 256, blk, 0, stream>>>(w12_w, W2p, 1024, 2730, 1024, 2730, tot);
  tot = 1024 * 2816; cvt_pad_kernel<<<(tot + 255) / 256, blk, 0, stream>>>(w3_w, W3b, 2816, 1024, 2730, 0, tot);
  norm_mod_kernel<<<8192, blk, 0, stream>>>(Xcur, Xn, norm3w, modsb, 6, 0);
  gemm_w12_swiglu<<<dim3(22, 64), blk, 0, stream>>>(Xn, W1p, W2p, w12_b, BIG);
  gemm_bt<0><<<dim3(8, 64), blk, 0, stream>>>(BIG, W3b, w3_b, P, 8192, 1024, 2816, 1024);
  resid_kernel<<<32768, blk, 0, stream>>>(Xcur, P, modsb, 8, out, 0);
}

// Round 3
// 937.035 us; speedup vs baseline: 1.2826x; 1.2826x over previous
//
#include <hip/hip_runtime.h>
#include <cstdint>
#include <cstddef>

typedef unsigned short u16;
typedef __attribute__((ext_vector_type(8))) short short8;
typedef __attribute__((ext_vector_type(4))) float f32x4;

// ---------- bf16 helpers (OCP bf16 = top 16 bits of fp32, RNE) ----------
__device__ __forceinline__ float bf2f(u16 u) {
  union { uint32_t u; float f; } x; x.u = ((uint32_t)u) << 16; return x.f;
}
__device__ __forceinline__ u16 f2bf(float f) {
  union { float f; uint32_t u; } x; x.f = f;
  uint32_t r = x.u + 0x7FFFu + ((x.u >> 16) & 1u);
  return (u16)(r >> 16);
}
__device__ __forceinline__ float silu_f(float x) { return x / (1.f + __expf(-x)); }

// async global->LDS, 16 B per lane; LDS dst = wave-uniform base + lane*16
__device__ __forceinline__ void glds16(const u16* g, u16* l) {
  __builtin_amdgcn_global_load_lds(
      (const __attribute__((address_space(1))) void*)g,
      (__attribute__((address_space(3))) void*)l, 16, 0, 0);
}

// ---------- weight fp32 -> bf16 convert with zero padding + row offset ----------
__global__ void cvt_pad_kernel(const float* __restrict__ in, u16* __restrict__ out,
                               int cols_out, int rows_in, int cols_in, int row_off, int total) {
  int i = blockIdx.x * 256 + threadIdx.x;
  if (i >= total) return;
  int r = i / cols_out, ci = i - r * cols_out;
  float v = 0.f;
  if (r < rows_in && ci < cols_in) v = in[(size_t)(r + row_off) * cols_in + ci];
  out[i] = f2bf(v);
}

// ---------- mods = silu(c) @ ada_w.T + ada_b   (B=2, 9216 outputs each) ----------
__global__ void mods_kernel(const float* __restrict__ c, const float* __restrict__ ada_w,
                            const float* __restrict__ ada_b, float* __restrict__ mods) {
  int j = blockIdx.x * 4 + (threadIdx.x >> 6);
  int lane = threadIdx.x & 63;
  float a0 = 0.f, a1 = 0.f;
  for (int k = lane; k < 1024; k += 64) {
    float w = ada_w[(size_t)j * 1024 + k];
    a0 += silu_f(c[k]) * w;
    a1 += silu_f(c[1024 + k]) * w;
  }
  #pragma unroll
  for (int off = 32; off > 0; off >>= 1) { a0 += __shfl_down(a0, off); a1 += __shfl_down(a1, off); }
  if (lane == 0) {
    float bb = ada_b[j];
    mods[j] = a0 + bb;
    mods[9216 + j] = a1 + bb;
  }
}

// ---------- rmsnorm(D=1024) * (1+sc) + sh  -> bf16 rows; optional (t,l) transpose ----------
__global__ __launch_bounds__(256) void norm_mod_kernel(
    const float* __restrict__ X, u16* __restrict__ Y,
    const float* __restrict__ nw, const float* __restrict__ mods,
    int sh_idx, int transpose) {
  int row = blockIdx.x;           // output row
  int b = row >> 12;
  int in_row;
  if (transpose) { int rem = row & 4095; int l = rem >> 4, t = rem & 15; in_row = (b << 12) + (t << 8) + l; }
  else in_row = row;
  int tid = threadIdx.x;
  float4 v = ((const float4*)(X + (size_t)in_row * 1024))[tid];
  float ss = v.x * v.x + v.y * v.y + v.z * v.z + v.w * v.w;
  #pragma unroll
  for (int off = 32; off > 0; off >>= 1) ss += __shfl_down(ss, off);
  __shared__ float red[4];
  if ((tid & 63) == 0) red[tid >> 6] = ss;
  __syncthreads();
  float rms = rsqrtf((red[0] + red[1] + red[2] + red[3]) * (1.f / 1024.f) + 1e-6f);
  const float* mb = mods + (size_t)b * 9216 + (size_t)sh_idx * 1024;
  float4 sh = ((const float4*)mb)[tid];
  float4 sc = ((const float4*)(mb + 1024))[tid];
  float4 w  = ((const float4*)nw)[tid];
  ushort4 o;
  o.x = f2bf(v.x * rms * w.x * (1.f + sc.x) + sh.x);
  o.y = f2bf(v.y * rms * w.y * (1.f + sc.y) + sh.y);
  o.z = f2bf(v.z * rms * w.z * (1.f + sc.z) + sh.z);
  o.w = f2bf(v.w * rms * w.w * (1.f + sc.w) + sh.w);
  ((ushort4*)(Y + (size_t)row * 1024))[tid] = o;
}

// ---------- bf16 MFMA GEMM (m97 structure): C[M,N] = A[M,K] @ W[N,K]^T + bias ----------
// 128x128 tile, 256 threads (4 waves). Unpadded 32-elem LDS rows, global_load_lds width 16.
template<int STORE_BF16>
__global__ __launch_bounds__(256) void gemm_bt(
    const u16* __restrict__ A, const u16* __restrict__ W,
    const float* __restrict__ bias, void* __restrict__ Cv,
    int M, int N, int K, int ldc) {
  __shared__ u16 As[128 * 32];
  __shared__ u16 Bs[128 * 32];
  int tid = threadIdx.x;
  int wid = tid >> 6, lane = tid & 63;
  int quad = lane >> 4, r = lane & 15;
  int m0 = blockIdx.y * 128, n0 = blockIdx.x * 128;
  int wm = (wid >> 1) * 64, wn = (wid & 1) * 64;
  int crow = lane >> 2, ccol = (lane & 3) * 8;

  f32x4 zero = {0.f, 0.f, 0.f, 0.f};
  f32x4 acc[4][4];
  #pragma unroll
  for (int i = 0; i < 4; i++)
    #pragma unroll
    for (int j = 0; j < 4; j++) acc[i][j] = zero;

  for (int k0 = 0; k0 < K; k0 += 32) {
    #pragma unroll
    for (int half = 0; half < 2; half++) {
      int chunk = wid + half * 4;          // wave-uniform
      int row = chunk * 16 + crow;
      glds16(A + (size_t)(m0 + row) * K + k0 + ccol, As + chunk * 512);
      glds16(W + (size_t)(n0 + row) * K + k0 + ccol, Bs + chunk * 512);
    }
    __syncthreads();
    short8 afr[4], bfr[4];
    #pragma unroll
    for (int i = 0; i < 4; i++) afr[i] = *(const short8*)(As + (wm + i * 16 + r) * 32 + quad * 8);
    #pragma unroll
    for (int j = 0; j < 4; j++) bfr[j] = *(const short8*)(Bs + (wn + j * 16 + r) * 32 + quad * 8);
    #pragma unroll
    for (int i = 0; i < 4; i++)
      #pragma unroll
      for (int j = 0; j < 4; j++)
        acc[i][j] = __builtin_amdgcn_mfma_f32_16x16x32_bf16(afr[i], bfr[j], acc[i][j], 0, 0, 0);
    __syncthreads();
  }

  float* Cf = (float*)Cv;
  u16* Ch = (u16*)Cv;
  #pragma unroll
  for (int i = 0; i < 4; i++) {
    #pragma unroll
    for (int j = 0; j < 4; j++) {
      int col = n0 + wn + j * 16 + r;
      if (col < N) {
        float bv = bias[col];
        #pragma unroll
        for (int rr = 0; rr < 4; rr++) {
          int row = m0 + wm + i * 16 + quad * 4 + rr;
          float vv = acc[i][j][rr] + bv;
          if (STORE_BF16) Ch[(size_t)row * ldc + col] = f2bf(vv);
          else            Cf[(size_t)row * ldc + col] = vv;
        }
      }
    }
  }
}

// ---------- fused w12 GEMM + SwiGLU (m97 staging): Hb = silu(A@W1^T+b1)*(A@W2^T+b2) ----------
__global__ __launch_bounds__(256) void gemm_w12_swiglu(
    const u16* __restrict__ A, const u16* __restrict__ W1, const u16* __restrict__ W2,
    const float* __restrict__ bias, u16* __restrict__ Hb) {
  __shared__ u16 As[128 * 32];
  __shared__ u16 B1s[128 * 32];
  __shared__ u16 B2s[128 * 32];
  int tid = threadIdx.x;
  int wid = tid >> 6, lane = tid & 63;
  int quad = lane >> 4, r = lane & 15;
  int m0 = blockIdx.y * 128, n0 = blockIdx.x * 128;
  int wm = (wid >> 1) * 64, wn = (wid & 1) * 64;
  int crow = lane >> 2, ccol = (lane & 3) * 8;

  f32x4 zero = {0.f, 0.f, 0.f, 0.f};
  f32x4 acc1[4][4], acc2[4][4];
  #pragma unroll
  for (int i = 0; i < 4; i++)
    #pragma unroll
    for (int j = 0; j < 4; j++) { acc1[i][j] = zero; acc2[i][j] = zero; }

  for (int k0 = 0; k0 < 1024; k0 += 32) {
    #pragma unroll
    for (int half = 0; half < 2; half++) {
      int chunk = wid + half * 4;
      int row = chunk * 16 + crow;
      glds16(A  + (size_t)(m0 + row) * 1024 + k0 + ccol, As  + chunk * 512);
      glds16(W1 + (size_t)(n0 + row) * 1024 + k0 + ccol, B1s + chunk * 512);
      glds16(W2 + (size_t)(n0 + row) * 1024 + k0 + ccol, B2s + chunk * 512);
    }
    __syncthreads();
    short8 afr[4], b1fr[4], b2fr[4];
    #pragma unroll
    for (int i = 0; i < 4; i++) afr[i]  = *(const short8*)(As  + (wm + i * 16 + r) * 32 + quad * 8);
    #pragma unroll
    for (int j = 0; j < 4; j++) b1fr[j] = *(const short8*)(B1s + (wn + j * 16 + r) * 32 + quad * 8);
    #pragma unroll
    for (int j = 0; j < 4; j++) b2fr[j] = *(const short8*)(B2s + (wn + j * 16 + r) * 32 + quad * 8);
    #pragma unroll
    for (int i = 0; i < 4; i++)
      #pragma unroll
      for (int j = 0; j < 4; j++) {
        acc1[i][j] = __builtin_amdgcn_mfma_f32_16x16x32_bf16(afr[i], b1fr[j], acc1[i][j], 0, 0, 0);
        acc2[i][j] = __builtin_amdgcn_mfma_f32_16x16x32_bf16(afr[i], b2fr[j], acc2[i][j], 0, 0, 0);
      }
    __syncthreads();
  }

  #pragma unroll
  for (int i = 0; i < 4; i++) {
    #pragma unroll
    for (int j = 0; j < 4; j++) {
      int col = n0 + wn + j * 16 + r;
      float b1 = (col < 2730) ? bias[col] : 0.f;
      float b2 = (col < 2730) ? bias[2730 + col] : 0.f;
      #pragma unroll
      for (int rr = 0; rr < 4; rr++) {
        int row = m0 + wm + i * 16 + quad * 4 + rr;
        float h1 = acc1[i][j][rr] + b1;
        float h2 = acc2[i][j][rr] + b2;
        Hb[(size_t)row * 2816 + col] = f2bf(silu_f(h1) * h2);
      }
    }
  }
}

// ---------- MFMA flash attention, spatial: seq=256, hd=64 ----------
// grid (512 pairs, 2 q-halves) x 256 thr. Wave handles 32 Q-rows vs all 256 KV.
// Fragment mappings identical to gemm_bt (HW-validated): A[m=lane&15][k=quad*8+j],
// B[n=lane&15][k=quad*8+j], C col=lane&15 row=quad*4+reg.
#define KSS 72    // Ks row stride (elems); 144 B = 9*16 -> aligned b128, 2-way banks
#define VSS 264   // Vt row stride; 528 B
#define PSS 40    // Pl row stride; 80 B
__global__ __launch_bounds__(256) void attn_s_mfma(
    const u16* __restrict__ QKV,   // 8192 x 3072 bf16 rows [q|k|v], 16 heads x 64
    const float* __restrict__ qn_w, const float* __restrict__ kn_w,
    const float* __restrict__ cosT, const float* __restrict__ sinT,  // 256 x 64
    u16* __restrict__ AO) {
  __shared__ u16 Ks[256 * KSS];       // 36864 B
  __shared__ u16 Vt[64 * VSS];        // 33792 B
  __shared__ u16 Pl[4 * 32 * PSS];    // 10240 B   (total 80896 B -> 2 blocks/CU)
  int pair = blockIdx.x;
  int s = pair >> 4, h = pair & 15;
  int qhalf = blockIdx.y;
  int tid = threadIdx.x, wid = tid >> 6, lane = tid & 63;
  int quad = lane >> 4, r = lane & 15;

  // ---- stage K (rmsnorm+rope, bf16) and V^T into LDS; thread = kv row ----
  {
    int j = tid;
    size_t rowb = ((size_t)(s * 256 + j)) * 3072 + (size_t)h * 64;
    const short8* kr = (const short8*)(QKV + rowb + 1024);
    float xk[64]; float ssq = 0.f;
    #pragma unroll
    for (int cg = 0; cg < 8; cg++) {
      short8 kk = kr[cg];
      #pragma unroll
      for (int e = 0; e < 8; e++) { float v = bf2f((u16)kk[e]); xk[cg * 8 + e] = v; ssq += v * v; }
    }
    float rms = rsqrtf(ssq * (1.f / 64.f) + 1e-6f);
    short8 kq[8];
    #pragma unroll
    for (int d = 0; d < 32; d++) {
      float a = xk[d] * rms * kn_w[d];
      float b2 = xk[d + 32] * rms * kn_w[d + 32];
      u16 o0 = f2bf(a * cosT[j * 64 + d] - b2 * sinT[j * 64 + d]);
      u16 o1 = f2bf(b2 * cosT[j * 64 + 32 + d] + a * sinT[j * 64 + 32 + d]);
      kq[d >> 3][d & 7] = (short)o0;
      kq[(d + 32) >> 3][d & 7] = (short)o1;
    }
    #pragma unroll
    for (int cg = 0; cg < 8; cg++) *(short8*)(Ks + j * KSS + cg * 8) = kq[cg];
    const short8* vr = (const short8*)(QKV + rowb + 2048);
    #pragma unroll
    for (int cg = 0; cg < 8; cg++) {
      short8 vv = vr[cg];
      #pragma unroll
      for (int e = 0; e < 8; e++) Vt[(cg * 8 + e) * VSS + j] = (u16)vv[e];
    }
  }

  // ---- Q fragments in registers: rows qbase+i*16+r, rmsnorm + rope ----
  int qbase = qhalf * 128 + wid * 32;
  short8 qa[2][2];      // [i][kstep]
  float lrow[2][4];
  {
    float qv[2][2][8];  // [i][kk][jj] fp32
    float ssq[2] = {0.f, 0.f};
    #pragma unroll
    for (int i = 0; i < 2; i++) {
      int grow = s * 256 + qbase + i * 16 + r;
      #pragma unroll
      for (int kk = 0; kk < 2; kk++) {
        short8 qraw = *(const short8*)(QKV + (size_t)grow * 3072 + h * 64 + kk * 32 + quad * 8);
        #pragma unroll
        for (int e = 0; e < 8; e++) { float v = bf2f((u16)qraw[e]); qv[i][kk][e] = v; ssq[i] += v * v; }
      }
    }
    #pragma unroll
    for (int i = 0; i < 2; i++) {
      float sv = ssq[i];
      sv += __shfl_xor(sv, 16);
      sv += __shfl_xor(sv, 32);
      float rms = rsqrtf(sv * (1.f / 64.f) + 1e-6f);
      int qrow = qbase + i * 16 + r;   // position in [0,256)
      #pragma unroll
      for (int e = 0; e < 8; e++) {
        int d0 = quad * 8 + e;         // < 32
        float a = qv[i][0][e] * rms * qn_w[d0];
        float b2 = qv[i][1][e] * rms * qn_w[d0 + 32];
        qa[i][0][e] = (short)f2bf(a * cosT[qrow * 64 + d0] - b2 * sinT[qrow * 64 + d0]);
        qa[i][1][e] = (short)f2bf(b2 * cosT[qrow * 64 + 32 + d0] + a * sinT[qrow * 64 + 32 + d0]);
      }
    }
  }
  __syncthreads();

  // ---- S = Q K^T : acc[i][j] = S[qbase+i*16+*][j*16+*] ----
  f32x4 zero = {0.f, 0.f, 0.f, 0.f};
  f32x4 acc[2][16];
  #pragma unroll
  for (int i = 0; i < 2; i++)
    #pragma unroll
    for (int j = 0; j < 16; j++) acc[i][j] = zero;
  #pragma unroll
  for (int kk = 0; kk < 2; kk++) {
    #pragma unroll
    for (int j = 0; j < 16; j++) {
      short8 bfr = *(const short8*)(Ks + (j * 16 + r) * KSS + kk * 32 + quad * 8);
      acc[0][j] = __builtin_amdgcn_mfma_f32_16x16x32_bf16(qa[0][kk], bfr, acc[0][j], 0, 0, 0);
      acc[1][j] = __builtin_amdgcn_mfma_f32_16x16x32_bf16(qa[1][kk], bfr, acc[1][j], 0, 0, 0);
    }
  }

  // ---- softmax over 256 cols (C-layout rows: quad*4+rr; cols: lane&15 across j) ----
  #pragma unroll
  for (int i = 0; i < 2; i++) {
    #pragma unroll
    for (int rr = 0; rr < 4; rr++) {
      float mx = acc[i][0][rr];
      #pragma unroll
      for (int j = 1; j < 16; j++) mx = fmaxf(mx, acc[i][j][rr]);
      #pragma unroll
      for (int msk = 1; msk < 16; msk <<= 1) mx = fmaxf(mx, __shfl_xor(mx, msk));
      float ls = 0.f;
      #pragma unroll
      for (int j = 0; j < 16; j++) { float p = __expf((acc[i][j][rr] - mx) * 0.125f); acc[i][j][rr] = p; ls += p; }
      #pragma unroll
      for (int msk = 1; msk < 16; msk <<= 1) ls += __shfl_xor(ls, msk);
      lrow[i][rr] = ls;
    }
  }

  // ---- O = P V via LDS round-trip per 32-kv step ----
  f32x4 oacc[2][4];
  #pragma unroll
  for (int i = 0; i < 2; i++)
    #pragma unroll
    for (int j = 0; j < 4; j++) oacc[i][j] = zero;
  u16* plw = Pl + wid * 32 * PSS;
  #pragma unroll
  for (int kk = 0; kk < 8; kk++) {
    #pragma unroll
    for (int i = 0; i < 2; i++)
      #pragma unroll
      for (int jj = 0; jj < 2; jj++) {
        int j = kk * 2 + jj;
        #pragma unroll
        for (int rr = 0; rr < 4; rr++)
          plw[(i * 16 + quad * 4 + rr) * PSS + jj * 16 + r] = f2bf(acc[i][j][rr]);
      }
    short8 pa0 = *(const short8*)(plw + r * PSS + quad * 8);
    short8 pa1 = *(const short8*)(plw + (16 + r) * PSS + quad * 8);
    #pragma unroll
    for (int j4 = 0; j4 < 4; j4++) {
      short8 vfr = *(const short8*)(Vt + (j4 * 16 + r) * VSS + kk * 32 + quad * 8);
      oacc[0][j4] = __builtin_amdgcn_mfma_f32_16x16x32_bf16(pa0, vfr, oacc[0][j4], 0, 0, 0);
      oacc[1][j4] = __builtin_amdgcn_mfma_f32_16x16x32_bf16(pa1, vfr, oacc[1][j4], 0, 0, 0);
    }
  }

  // ---- epilogue: normalize by l, store bf16 ----
  #pragma unroll
  for (int i = 0; i < 2; i++) {
    #pragma unroll
    for (int rr = 0; rr < 4; rr++) {
      float inv = 1.f / lrow[i][rr];
      int row = s * 256 + qbase + i * 16 + quad * 4 + rr;
      #pragma unroll
      for (int j4 = 0; j4 < 4; j4++)
        AO[(size_t)row * 1024 + h * 64 + j4 * 16 + r] = f2bf(oacc[i][j4][rr] * inv);
    }
  }
}

// ---------- temporal attention: seq=16, block per (b,l), thread = (head, t) ----------
__global__ __launch_bounds__(256) void attn_t_kernel(
    const u16* __restrict__ QKV,
    const float* __restrict__ qn_w, const float* __restrict__ kn_w,
    const float* __restrict__ cosT, const float* __restrict__ sinT,
    u16* __restrict__ AO) {
  __shared__ u16 kb[256 * 64];
  __shared__ u16 vb[256 * 64];
  int bl = blockIdx.x;
  int tid = threadIdx.x;
  int h = tid >> 4, t = tid & 15;
  size_t rowbase = ((size_t)(bl * 16 + t)) * 3072;
  int slot = h * 16 + t;
  {
    const u16* kr = QKV + rowbase + 1024 + h * 64;
    float xk[64]; float ss = 0.f;
    #pragma unroll
    for (int d = 0; d < 64; d++) { xk[d] = bf2f(kr[d]); ss += xk[d] * xk[d]; }
    float rms = rsqrtf(ss * (1.f / 64.f) + 1e-6f);
    #pragma unroll
    for (int d = 0; d < 64; d++) xk[d] *= rms * kn_w[d];
    #pragma unroll
    for (int d = 0; d < 32; d++) {
      float a = xk[d], bb = xk[d + 32];
      kb[slot * 64 + d]      = f2bf(a * cosT[t * 64 + d]       - bb * sinT[t * 64 + d]);
      kb[slot * 64 + 32 + d] = f2bf(bb * cosT[t * 64 + 32 + d] + a * sinT[t * 64 + 32 + d]);
    }
    const u16* vr = QKV + rowbase + 2048 + h * 64;
    #pragma unroll
    for (int d = 0; d < 64; d++) vb[slot * 64 + d] = vr[d];
  }
  float q[64];
  {
    const u16* qr = QKV + rowbase + h * 64;
    float ss = 0.f;
    #pragma unroll
    for (int d = 0; d < 64; d++) { q[d] = bf2f(qr[d]); ss += q[d] * q[d]; }
    float rms = rsqrtf(ss * (1.f / 64.f) + 1e-6f);
    #pragma unroll
    for (int d = 0; d < 64; d++) q[d] *= rms * qn_w[d];
    #pragma unroll
    for (int d = 0; d < 32; d++) {
      float a = q[d], bb = q[d + 32];
      q[d]      = a * cosT[t * 64 + d]       - bb * sinT[t * 64 + d];
      q[d + 32] = bb * cosT[t * 64 + 32 + d] + a * sinT[t * 64 + 32 + d];
    }
  }
  __syncthreads();
  float scv[16]; float mx = -1e30f;
  #pragma unroll
  for (int j = 0; j < 16; j++) {
    float sc = 0.f;
    const short8* krow = (const short8*)(kb + (h * 16 + j) * 64);
    #pragma unroll
    for (int vv = 0; vv < 8; vv++) {
      short8 kk = krow[vv];
      #pragma unroll
      for (int e = 0; e < 8; e++) sc += q[vv * 8 + e] * bf2f((u16)kk[e]);
    }
    scv[j] = sc * 0.125f;
    mx = fmaxf(mx, scv[j]);
  }
  float ssum = 0.f;
  #pragma unroll
  for (int j = 0; j < 16; j++) { scv[j] = __expf(scv[j] - mx); ssum += scv[j]; }
  float inv = 1.f / ssum;
  float o[64];
  #pragma unroll
  for (int d = 0; d < 64; d++) o[d] = 0.f;
  #pragma unroll
  for (int j = 0; j < 16; j++) {
    const short8* vrow = (const short8*)(vb + (h * 16 + j) * 64);
    #pragma unroll
    for (int vv = 0; vv < 8; vv++) {
      short8 vk = vrow[vv];
      #pragma unroll
      for (int e = 0; e < 8; e++) o[vv * 8 + e] += scv[j] * bf2f((u16)vk[e]);
    }
  }
  u16* op = AO + ((size_t)(bl * 16 + t)) * 1024 + h * 64;
  #pragma unroll
  for (int d = 0; d < 64; d++) op[d] = f2bf(o[d] * inv);
}

// ---------- residual: out = base + g[b,d] * P (optional (b,l,t)->(b,t,l) gather of P) ----------
__global__ void resid_kernel(const float* __restrict__ base, const float* __restrict__ P,
                             const float* __restrict__ mods, int gidx,
                             float* __restrict__ out, int transpose) {
  int e = blockIdx.x * 256 + threadIdx.x;
  int row = e >> 10, d = e & 1023;
  int b = row >> 12;
  float g = mods[(size_t)b * 9216 + (size_t)gidx * 1024 + d];
  float p;
  if (transpose) {
    int rem = row & 4095; int t = rem >> 8, l = rem & 255;
    size_t mp = ((size_t)(b << 12)) + (l << 4) + t;
    p = P[(mp << 10) + d];
  } else p = P[e];
  out[e] = base[e] + g * p;
}

// =====================================================================
extern "C" void kernel_launch(void* const* d_in, const int* in_sizes, int n_in,
                              void* d_out, int out_size, void* d_ws, size_t ws_size,
                              hipStream_t stream) {
  const float* x        = (const float*)d_in[0];
  const float* c        = (const float*)d_in[1];
  const float* cos_s    = (const float*)d_in[2];
  const float* sin_s    = (const float*)d_in[3];
  const float* cos_t    = (const float*)d_in[4];
  const float* sin_t    = (const float*)d_in[5];
  const float* norm1w   = (const float*)d_in[6];
  const float* norm2w   = (const float*)d_in[7];
  const float* norm3w   = (const float*)d_in[8];
  const float* qkv_s_w  = (const float*)d_in[9];
  const float* qkv_s_b  = (const float*)d_in[10];
  const float* qn_s_w   = (const float*)d_in[11];
  const float* kn_s_w   = (const float*)d_in[12];
  const float* proj_s_w = (const float*)d_in[13];
  const float* proj_s_b = (const float*)d_in[14];
  const float* qkv_t_w  = (const float*)d_in[15];
  const float* qkv_t_b  = (const float*)d_in[16];
  const float* qn_t_w   = (const float*)d_in[17];
  const float* kn_t_w   = (const float*)d_in[18];
  const float* proj_t_w = (const float*)d_in[19];
  const float* proj_t_b = (const float*)d_in[20];
  const float* w12_w    = (const float*)d_in[21];
  const float* w12_b    = (const float*)d_in[22];
  const float* w3_w     = (const float*)d_in[23];
  const float* w3_b     = (const float*)d_in[24];
  const float* ada_w    = (const float*)d_in[25];
  const float* ada_b    = (const float*)d_in[26];
  float* out = (float*)d_out;

  // ---- workspace layout: ~112.6 MiB ----
  char* wsp = (char*)d_ws;
  size_t off = 0;
  auto alloc = [&](size_t bytes) { size_t p = off; off += (bytes + 255) & ~(size_t)255; return p; };
  float* modsb = (float*)(wsp + alloc(2 * 9216 * 4));
  u16*   BIG   = (u16*)  (wsp + alloc((size_t)8192 * 3072 * 2));  // QKV (st1,2) / Hb 8192x2816 (st3)
  char*  XnP   = (char*) (wsp + alloc((size_t)8192 * 1024 * 4));  // Xn bf16 <-> P fp32
  u16*   AO    = (u16*)  (wsp + alloc((size_t)8192 * 1024 * 2));
  u16*   Wq    = (u16*)  (wsp + alloc((size_t)3072 * 1024 * 2));
  u16*   Wp    = (u16*)  (wsp + alloc((size_t)2816 * 1024 * 2));
  u16*   W3b   = (u16*)  (wsp + alloc((size_t)1024 * 2816 * 2));
  u16* W1p = Wq;
  u16* W2p = Wp;
  u16* Xn  = (u16*)XnP;
  float* P = (float*)XnP;
  float* Xcur = out;   // residual stream lives in d_out

  dim3 blk(256);
  int tot;
  mods_kernel<<<2304, blk, 0, stream>>>(c, ada_w, ada_b, modsb);

  // ---- stage 1: spatial attention ----
  tot = 3072 * 1024; cvt_pad_kernel<<<(tot + 255) / 256, blk, 0, stream>>>(qkv_s_w, Wq, 1024, 3072, 1024, 0, tot);
  tot = 1024 * 1024; cvt_pad_kernel<<<(tot + 255) / 256, blk, 0, stream>>>(proj_s_w, Wp, 1024, 1024, 1024, 0, tot);
  norm_mod_kernel<<<8192, blk, 0, stream>>>(x, Xn, norm1w, modsb, 0, 0);
  gemm_bt<1><<<dim3(24, 64), blk, 0, stream>>>(Xn, Wq, qkv_s_b, BIG, 8192, 3072, 1024, 3072);
  attn_s_mfma<<<dim3(512, 2), blk, 0, stream>>>(BIG, qn_s_w, kn_s_w, cos_s, sin_s, AO);
  gemm_bt<0><<<dim3(8, 64), blk, 0, stream>>>(AO, Wp, proj_s_b, P, 8192, 1024, 1024, 1024);
  resid_kernel<<<32768, blk, 0, stream>>>(x, P, modsb, 2, Xcur, 0);

  // ---- stage 2: temporal attention (rows in (b,l,t) order) ----
  tot = 3072 * 1024; cvt_pad_kernel<<<(tot + 255) / 256, blk, 0, stream>>>(qkv_t_w, Wq, 1024, 3072, 1024, 0, tot);
  tot = 1024 * 1024; cvt_pad_kernel<<<(tot + 255) / 256, blk, 0, stream>>>(proj_t_w, Wp, 1024, 1024, 1024, 0, tot);
  norm_mod_kernel<<<8192, blk, 0, stream>>>(Xcur, Xn, norm2w, modsb, 3, 1);
  gemm_bt<1><<<dim3(24, 64), blk, 0, stream>>>(Xn, Wq, qkv_t_b, BIG, 8192, 3072, 1024, 3072);
  attn_t_kernel<<<512, blk, 0, stream>>>(BIG, qn_t_w, kn_t_w, cos_t, sin_t, AO);
  gemm_bt<0><<<dim3(8, 64), blk, 0, stream>>>(AO, Wp, proj_t_b, P, 8192, 1024, 1024, 1024);
  resid_kernel<<<32768, blk, 0, stream>>>(Xcur, P, modsb, 5, Xcur, 1);

  // ---- stage 3: SwiGLU MLP (HFF 2730 padded to 2816) ----
  tot = 2816 * 1024; cvt_pad_kernel<<<(tot + 255) / 256, blk, 0, stream>>>(w12_w, W1p, 1024, 2730, 1024, 0, tot);
  tot = 2816 * 1024; cvt_pad_kernel<<<(tot + 255) / 256, blk, 0, stream>>>(w12_w, W2p, 1024, 2730, 1024, 2730, tot);
  tot = 1024 * 2816; cvt_pad_kernel<<<(tot + 255) / 256, blk, 0, stream>>>(w3_w, W3b, 2816, 1024, 2730, 0, tot);
  norm_mod_kernel<<<8192, blk, 0, stream>>>(Xcur, Xn, norm3w, modsb, 6, 0);
  gemm_w12_swiglu<<<dim3(22, 64), blk, 0, stream>>>(Xn, W1p, W2p, w12_b, BIG);
  gemm_bt<0><<<dim3(8, 64), blk, 0, stream>>>(BIG, W3b, w3_b, P, 8192, 1024, 2816, 1024);
  resid_kernel<<<32768, blk, 0, stream>>>(Xcur, P, modsb, 8, out, 0);
}

// Round 5
// 919.205 us; speedup vs baseline: 1.3075x; 1.0194x over previous
//
#include <hip/hip_runtime.h>
#include <cstdint>
#include <cstddef>

typedef unsigned short u16;
typedef __attribute__((ext_vector_type(8))) short short8;
typedef __attribute__((ext_vector_type(4))) float f32x4;

// ---------- bf16 helpers (OCP bf16 = top 16 bits of fp32, RNE) ----------
__device__ __forceinline__ float bf2f(u16 u) {
  union { uint32_t u; float f; } x; x.u = ((uint32_t)u) << 16; return x.f;
}
__device__ __forceinline__ u16 f2bf(float f) {
  union { float f; uint32_t u; } x; x.f = f;
  uint32_t r = x.u + 0x7FFFu + ((x.u >> 16) & 1u);
  return (u16)(r >> 16);
}
__device__ __forceinline__ float silu_f(float x) { return x / (1.f + __expf(-x)); }

// async global->LDS, 16 B per lane; LDS dst = wave-uniform base + lane*16
__device__ __forceinline__ void glds16(const u16* g, u16* l) {
  __builtin_amdgcn_global_load_lds(
      (const __attribute__((address_space(1))) void*)g,
      (__attribute__((address_space(3))) void*)l, 16, 0, 0);
}

// XCD m-strip swizzle: XCD (bid%8) owns m-tiles [xcd*8, xcd*8+8) x all n-tiles,
// m-fastest within the strip so the 2MB A-strip stays hot in the 4MB per-XCD L2.
// Pure bijection [0, 8*gridDim.y) -> (mt in [0,64), nt in [0,gridDim.x)).
__device__ __forceinline__ void swizzle_mn(int nx, int& mt, int& nt) {
  int bid = blockIdx.y * nx + blockIdx.x;
  int xcd = bid & 7, l = bid >> 3;
  nt = l >> 3;
  mt = (xcd << 3) | (l & 7);
}

// ---------- weight fp32 -> bf16 convert with zero padding + row offset ----------
__global__ void cvt_pad_kernel(const float* __restrict__ in, u16* __restrict__ out,
                               int cols_out, int rows_in, int cols_in, int row_off, int total) {
  int i = blockIdx.x * 256 + threadIdx.x;
  if (i >= total) return;
  int r = i / cols_out, ci = i - r * cols_out;
  float v = 0.f;
  if (r < rows_in && ci < cols_in) v = in[(size_t)(r + row_off) * cols_in + ci];
  out[i] = f2bf(v);
}

// ---------- mods = silu(c) @ ada_w.T + ada_b   (B=2, 9216 outputs each) ----------
__global__ void mods_kernel(const float* __restrict__ c, const float* __restrict__ ada_w,
                            const float* __restrict__ ada_b, float* __restrict__ mods) {
  int j = blockIdx.x * 4 + (threadIdx.x >> 6);
  int lane = threadIdx.x & 63;
  float a0 = 0.f, a1 = 0.f;
  for (int k = lane; k < 1024; k += 64) {
    float w = ada_w[(size_t)j * 1024 + k];
    a0 += silu_f(c[k]) * w;
    a1 += silu_f(c[1024 + k]) * w;
  }
  #pragma unroll
  for (int off = 32; off > 0; off >>= 1) { a0 += __shfl_down(a0, off); a1 += __shfl_down(a1, off); }
  if (lane == 0) {
    float bb = ada_b[j];
    mods[j] = a0 + bb;
    mods[9216 + j] = a1 + bb;
  }
}

// ---------- rmsnorm(D=1024) * (1+sc) + sh  -> bf16 rows; optional (t,l) transpose ----------
__global__ __launch_bounds__(256) void norm_mod_kernel(
    const float* __restrict__ X, u16* __restrict__ Y,
    const float* __restrict__ nw, const float* __restrict__ mods,
    int sh_idx, int transpose) {
  int row = blockIdx.x;           // output row
  int b = row >> 12;
  int in_row;
  if (transpose) { int rem = row & 4095; int l = rem >> 4, t = rem & 15; in_row = (b << 12) + (t << 8) + l; }
  else in_row = row;
  int tid = threadIdx.x;
  float4 v = ((const float4*)(X + (size_t)in_row * 1024))[tid];
  float ss = v.x * v.x + v.y * v.y + v.z * v.z + v.w * v.w;
  #pragma unroll
  for (int off = 32; off > 0; off >>= 1) ss += __shfl_down(ss, off);
  __shared__ float red[4];
  if ((tid & 63) == 0) red[tid >> 6] = ss;
  __syncthreads();
  float rms = rsqrtf((red[0] + red[1] + red[2] + red[3]) * (1.f / 1024.f) + 1e-6f);
  const float* mb = mods + (size_t)b * 9216 + (size_t)sh_idx * 1024;
  float4 sh = ((const float4*)mb)[tid];
  float4 sc = ((const float4*)(mb + 1024))[tid];
  float4 w  = ((const float4*)nw)[tid];
  ushort4 o;
  o.x = f2bf(v.x * rms * w.x * (1.f + sc.x) + sh.x);
  o.y = f2bf(v.y * rms * w.y * (1.f + sc.y) + sh.y);
  o.z = f2bf(v.z * rms * w.z * (1.f + sc.z) + sh.z);
  o.w = f2bf(v.w * rms * w.w * (1.f + sc.w) + sh.w);
  ((ushort4*)(Y + (size_t)row * 1024))[tid] = o;
}

// ---------- bf16 MFMA GEMM (m97 structure + XCD swizzle): C[M,N] = A[M,K] @ W[N,K]^T + bias ----------
// 128x128 tile, 256 threads (4 waves). Unpadded 32-elem LDS rows, global_load_lds width 16.
template<int STORE_BF16>
__global__ __launch_bounds__(256) void gemm_bt(
    const u16* __restrict__ A, const u16* __restrict__ W,
    const float* __restrict__ bias, void* __restrict__ Cv,
    int N, int K, int ldc) {
  __shared__ u16 As[128 * 32];
  __shared__ u16 Bs[128 * 32];
  int tid = threadIdx.x;
  int wid = tid >> 6, lane = tid & 63;
  int quad = lane >> 4, r = lane & 15;
  int mt, nt; swizzle_mn(gridDim.x, mt, nt);
  int m0 = mt * 128, n0 = nt * 128;
  int wm = (wid >> 1) * 64, wn = (wid & 1) * 64;
  int crow = lane >> 2, ccol = (lane & 3) * 8;

  f32x4 zero = {0.f, 0.f, 0.f, 0.f};
  f32x4 acc[4][4];
  #pragma unroll
  for (int i = 0; i < 4; i++)
    #pragma unroll
    for (int j = 0; j < 4; j++) acc[i][j] = zero;

  for (int k0 = 0; k0 < K; k0 += 32) {
    #pragma unroll
    for (int half = 0; half < 2; half++) {
      int chunk = wid + half * 4;          // wave-uniform
      int row = chunk * 16 + crow;
      glds16(A + (size_t)(m0 + row) * K + k0 + ccol, As + chunk * 512);
      glds16(W + (size_t)(n0 + row) * K + k0 + ccol, Bs + chunk * 512);
    }
    __syncthreads();
    short8 afr[4], bfr[4];
    #pragma unroll
    for (int i = 0; i < 4; i++) afr[i] = *(const short8*)(As + (wm + i * 16 + r) * 32 + quad * 8);
    #pragma unroll
    for (int j = 0; j < 4; j++) bfr[j] = *(const short8*)(Bs + (wn + j * 16 + r) * 32 + quad * 8);
    #pragma unroll
    for (int i = 0; i < 4; i++)
      #pragma unroll
      for (int j = 0; j < 4; j++)
        acc[i][j] = __builtin_amdgcn_mfma_f32_16x16x32_bf16(afr[i], bfr[j], acc[i][j], 0, 0, 0);
    __syncthreads();
  }

  float* Cf = (float*)Cv;
  u16* Ch = (u16*)Cv;
  #pragma unroll
  for (int i = 0; i < 4; i++) {
    #pragma unroll
    for (int j = 0; j < 4; j++) {
      int col = n0 + wn + j * 16 + r;
      float bv = bias[col];
      #pragma unroll
      for (int rr = 0; rr < 4; rr++) {
        int row = m0 + wm + i * 16 + quad * 4 + rr;
        float vv = acc[i][j][rr] + bv;
        if (STORE_BF16) Ch[(size_t)row * ldc + col] = f2bf(vv);
        else            Cf[(size_t)row * ldc + col] = vv;
      }
    }
  }
}

// ---------- fused w12 GEMM + SwiGLU (m97 staging + swizzle) ----------
__global__ __launch_bounds__(256) void gemm_w12_swiglu(
    const u16* __restrict__ A, const u16* __restrict__ W1, const u16* __restrict__ W2,
    const float* __restrict__ bias, u16* __restrict__ Hb) {
  __shared__ u16 As[128 * 32];
  __shared__ u16 B1s[128 * 32];
  __shared__ u16 B2s[128 * 32];
  int tid = threadIdx.x;
  int wid = tid >> 6, lane = tid & 63;
  int quad = lane >> 4, r = lane & 15;
  int mt, nt; swizzle_mn(gridDim.x, mt, nt);
  int m0 = mt * 128, n0 = nt * 128;
  int wm = (wid >> 1) * 64, wn = (wid & 1) * 64;
  int crow = lane >> 2, ccol = (lane & 3) * 8;

  f32x4 zero = {0.f, 0.f, 0.f, 0.f};
  f32x4 acc1[4][4], acc2[4][4];
  #pragma unroll
  for (int i = 0; i < 4; i++)
    #pragma unroll
    for (int j = 0; j < 4; j++) { acc1[i][j] = zero; acc2[i][j] = zero; }

  for (int k0 = 0; k0 < 1024; k0 += 32) {
    #pragma unroll
    for (int half = 0; half < 2; half++) {
      int chunk = wid + half * 4;
      int row = chunk * 16 + crow;
      glds16(A  + (size_t)(m0 + row) * 1024 + k0 + ccol, As  + chunk * 512);
      glds16(W1 + (size_t)(n0 + row) * 1024 + k0 + ccol, B1s + chunk * 512);
      glds16(W2 + (size_t)(n0 + row) * 1024 + k0 + ccol, B2s + chunk * 512);
    }
    __syncthreads();
    short8 afr[4], b1fr[4], b2fr[4];
    #pragma unroll
    for (int i = 0; i < 4; i++) afr[i]  = *(const short8*)(As  + (wm + i * 16 + r) * 32 + quad * 8);
    #pragma unroll
    for (int j = 0; j < 4; j++) b1fr[j] = *(const short8*)(B1s + (wn + j * 16 + r) * 32 + quad * 8);
    #pragma unroll
    for (int j = 0; j < 4; j++) b2fr[j] = *(const short8*)(B2s + (wn + j * 16 + r) * 32 + quad * 8);
    #pragma unroll
    for (int i = 0; i < 4; i++)
      #pragma unroll
      for (int j = 0; j < 4; j++) {
        acc1[i][j] = __builtin_amdgcn_mfma_f32_16x16x32_bf16(afr[i], b1fr[j], acc1[i][j], 0, 0, 0);
        acc2[i][j] = __builtin_amdgcn_mfma_f32_16x16x32_bf16(afr[i], b2fr[j], acc2[i][j], 0, 0, 0);
      }
    __syncthreads();
  }

  #pragma unroll
  for (int i = 0; i < 4; i++) {
    #pragma unroll
    for (int j = 0; j < 4; j++) {
      int col = n0 + wn + j * 16 + r;
      float b1 = (col < 2730) ? bias[col] : 0.f;
      float b2 = (col < 2730) ? bias[2730 + col] : 0.f;
      #pragma unroll
      for (int rr = 0; rr < 4; rr++) {
        int row = m0 + wm + i * 16 + quad * 4 + rr;
        float h1 = acc1[i][j][rr] + b1;
        float h2 = acc2[i][j][rr] + b2;
        Hb[(size_t)row * 2816 + col] = f2bf(silu_f(h1) * h2);
      }
    }
  }
}

// ---------- MFMA flash attention, spatial: seq=256, hd=64 ----------
#define KSS 72
#define VSS 264
#define PSS 40
__global__ __launch_bounds__(256) void attn_s_mfma(
    const u16* __restrict__ QKV,
    const float* __restrict__ qn_w, const float* __restrict__ kn_w,
    const float* __restrict__ cosT, const float* __restrict__ sinT,
    u16* __restrict__ AO) {
  __shared__ u16 Ks[256 * KSS];
  __shared__ u16 Vt[64 * VSS];
  __shared__ u16 Pl[4 * 32 * PSS];
  int pair = blockIdx.x;
  int s = pair >> 4, h = pair & 15;
  int qhalf = blockIdx.y;
  int tid = threadIdx.x, wid = tid >> 6, lane = tid & 63;
  int quad = lane >> 4, r = lane & 15;

  {
    int j = tid;
    size_t rowb = ((size_t)(s * 256 + j)) * 3072 + (size_t)h * 64;
    const short8* kr = (const short8*)(QKV + rowb + 1024);
    float xk[64]; float ssq = 0.f;
    #pragma unroll
    for (int cg = 0; cg < 8; cg++) {
      short8 kk = kr[cg];
      #pragma unroll
      for (int e = 0; e < 8; e++) { float v = bf2f((u16)kk[e]); xk[cg * 8 + e] = v; ssq += v * v; }
    }
    float rms = rsqrtf(ssq * (1.f / 64.f) + 1e-6f);
    short8 kq[8];
    #pragma unroll
    for (int d = 0; d < 32; d++) {
      float a = xk[d] * rms * kn_w[d];
      float b2 = xk[d + 32] * rms * kn_w[d + 32];
      u16 o0 = f2bf(a * cosT[j * 64 + d] - b2 * sinT[j * 64 + d]);
      u16 o1 = f2bf(b2 * cosT[j * 64 + 32 + d] + a * sinT[j * 64 + 32 + d]);
      kq[d >> 3][d & 7] = (short)o0;
      kq[(d + 32) >> 3][d & 7] = (short)o1;
    }
    #pragma unroll
    for (int cg = 0; cg < 8; cg++) *(short8*)(Ks + j * KSS + cg * 8) = kq[cg];
    const short8* vr = (const short8*)(QKV + rowb + 2048);
    #pragma unroll
    for (int cg = 0; cg < 8; cg++) {
      short8 vv = vr[cg];
      #pragma unroll
      for (int e = 0; e < 8; e++) Vt[(cg * 8 + e) * VSS + j] = (u16)vv[e];
    }
  }

  int qbase = qhalf * 128 + wid * 32;
  short8 qa[2][2];
  float lrow[2][4];
  {
    float qv[2][2][8];
    float ssq[2] = {0.f, 0.f};
    #pragma unroll
    for (int i = 0; i < 2; i++) {
      int grow = s * 256 + qbase + i * 16 + r;
      #pragma unroll
      for (int kk = 0; kk < 2; kk++) {
        short8 qraw = *(const short8*)(QKV + (size_t)grow * 3072 + h * 64 + kk * 32 + quad * 8);
        #pragma unroll
        for (int e = 0; e < 8; e++) { float v = bf2f((u16)qraw[e]); qv[i][kk][e] = v; ssq[i] += v * v; }
      }
    }
    #pragma unroll
    for (int i = 0; i < 2; i++) {
      float sv = ssq[i];
      sv += __shfl_xor(sv, 16);
      sv += __shfl_xor(sv, 32);
      float rms = rsqrtf(sv * (1.f / 64.f) + 1e-6f);
      int qrow = qbase + i * 16 + r;
      #pragma unroll
      for (int e = 0; e < 8; e++) {
        int d0 = quad * 8 + e;
        float a = qv[i][0][e] * rms * qn_w[d0];
        float b2 = qv[i][1][e] * rms * qn_w[d0 + 32];
        qa[i][0][e] = (short)f2bf(a * cosT[qrow * 64 + d0] - b2 * sinT[qrow * 64 + d0]);
        qa[i][1][e] = (short)f2bf(b2 * cosT[qrow * 64 + 32 + d0] + a * sinT[qrow * 64 + 32 + d0]);
      }
    }
  }
  __syncthreads();

  f32x4 zero = {0.f, 0.f, 0.f, 0.f};
  f32x4 acc[2][16];
  #pragma unroll
  for (int i = 0; i < 2; i++)
    #pragma unroll
    for (int j = 0; j < 16; j++) acc[i][j] = zero;
  #pragma unroll
  for (int kk = 0; kk < 2; kk++) {
    #pragma unroll
    for (int j = 0; j < 16; j++) {
      short8 bfr = *(const short8*)(Ks + (j * 16 + r) * KSS + kk * 32 + quad * 8);
      acc[0][j] = __builtin_amdgcn_mfma_f32_16x16x32_bf16(qa[0][kk], bfr, acc[0][j], 0, 0, 0);
      acc[1][j] = __builtin_amdgcn_mfma_f32_16x16x32_bf16(qa[1][kk], bfr, acc[1][j], 0, 0, 0);
    }
  }

  #pragma unroll
  for (int i = 0; i < 2; i++) {
    #pragma unroll
    for (int rr = 0; rr < 4; rr++) {
      float mx = acc[i][0][rr];
      #pragma unroll
      for (int j = 1; j < 16; j++) mx = fmaxf(mx, acc[i][j][rr]);
      #pragma unroll
      for (int msk = 1; msk < 16; msk <<= 1) mx = fmaxf(mx, __shfl_xor(mx, msk));
      float ls = 0.f;
      #pragma unroll
      for (int j = 0; j < 16; j++) { float p = __expf((acc[i][j][rr] - mx) * 0.125f); acc[i][j][rr] = p; ls += p; }
      #pragma unroll
      for (int msk = 1; msk < 16; msk <<= 1) ls += __shfl_xor(ls, msk);
      lrow[i][rr] = ls;
    }
  }

  f32x4 oacc[2][4];
  #pragma unroll
  for (int i = 0; i < 2; i++)
    #pragma unroll
    for (int j = 0; j < 4; j++) oacc[i][j] = zero;
  u16* plw = Pl + wid * 32 * PSS;
  #pragma unroll
  for (int kk = 0; kk < 8; kk++) {
    #pragma unroll
    for (int i = 0; i < 2; i++)
      #pragma unroll
      for (int jj = 0; jj < 2; jj++) {
        int j = kk * 2 + jj;
        #pragma unroll
        for (int rr = 0; rr < 4; rr++)
          plw[(i * 16 + quad * 4 + rr) * PSS + jj * 16 + r] = f2bf(acc[i][j][rr]);
      }
    short8 pa0 = *(const short8*)(plw + r * PSS + quad * 8);
    short8 pa1 = *(const short8*)(plw + (16 + r) * PSS + quad * 8);
    #pragma unroll
    for (int j4 = 0; j4 < 4; j4++) {
      short8 vfr = *(const short8*)(Vt + (j4 * 16 + r) * VSS + kk * 32 + quad * 8);
      oacc[0][j4] = __builtin_amdgcn_mfma_f32_16x16x32_bf16(pa0, vfr, oacc[0][j4], 0, 0, 0);
      oacc[1][j4] = __builtin_amdgcn_mfma_f32_16x16x32_bf16(pa1, vfr, oacc[1][j4], 0, 0, 0);
    }
  }

  #pragma unroll
  for (int i = 0; i < 2; i++) {
    #pragma unroll
    for (int rr = 0; rr < 4; rr++) {
      float inv = 1.f / lrow[i][rr];
      int row = s * 256 + qbase + i * 16 + quad * 4 + rr;
      #pragma unroll
      for (int j4 = 0; j4 < 4; j4++)
        AO[(size_t)row * 1024 + h * 64 + j4 * 16 + r] = f2bf(oacc[i][j4][rr] * inv);
    }
  }
}

// ---------- temporal attention: seq=16, block per (b,l), thread = (head, t) ----------
__global__ __launch_bounds__(256) void attn_t_kernel(
    const u16* __restrict__ QKV,
    const float* __restrict__ qn_w, const float* __restrict__ kn_w,
    const float* __restrict__ cosT, const float* __restrict__ sinT,
    u16* __restrict__ AO) {
  __shared__ u16 kb[256 * 64];
  __shared__ u16 vb[256 * 64];
  int bl = blockIdx.x;
  int tid = threadIdx.x;
  int h = tid >> 4, t = tid & 15;
  size_t rowbase = ((size_t)(bl * 16 + t)) * 3072;
  int slot = h * 16 + t;
  {
    const u16* kr = QKV + rowbase + 1024 + h * 64;
    float xk[64]; float ss = 0.f;
    #pragma unroll
    for (int d = 0; d < 64; d++) { xk[d] = bf2f(kr[d]); ss += xk[d] * xk[d]; }
    float rms = rsqrtf(ss * (1.f / 64.f) + 1e-6f);
    #pragma unroll
    for (int d = 0; d < 64; d++) xk[d] *= rms * kn_w[d];
    #pragma unroll
    for (int d = 0; d < 32; d++) {
      float a = xk[d], bb = xk[d + 32];
      kb[slot * 64 + d]      = f2bf(a * cosT[t * 64 + d]       - bb * sinT[t * 64 + d]);
      kb[slot * 64 + 32 + d] = f2bf(bb * cosT[t * 64 + 32 + d] + a * sinT[t * 64 + 32 + d]);
    }
    const u16* vr = QKV + rowbase + 2048 + h * 64;
    #pragma unroll
    for (int d = 0; d < 64; d++) vb[slot * 64 + d] = vr[d];
  }
  float q[64];
  {
    const u16* qr = QKV + rowbase + h * 64;
    float ss = 0.f;
    #pragma unroll
    for (int d = 0; d < 64; d++) { q[d] = bf2f(qr[d]); ss += q[d] * q[d]; }
    float rms = rsqrtf(ss * (1.f / 64.f) + 1e-6f);
    #pragma unroll
    for (int d = 0; d < 64; d++) q[d] *= rms * qn_w[d];
    #pragma unroll
    for (int d = 0; d < 32; d++) {
      float a = q[d], bb = q[d + 32];
      q[d]      = a * cosT[t * 64 + d]       - bb * sinT[t * 64 + d];
      q[d + 32] = bb * cosT[t * 64 + 32 + d] + a * sinT[t * 64 + 32 + d];
    }
  }
  __syncthreads();
  float scv[16]; float mx = -1e30f;
  #pragma unroll
  for (int j = 0; j < 16; j++) {
    float sc = 0.f;
    const short8* krow = (const short8*)(kb + (h * 16 + j) * 64);
    #pragma unroll
    for (int vv = 0; vv < 8; vv++) {
      short8 kk = krow[vv];
      #pragma unroll
      for (int e = 0; e < 8; e++) sc += q[vv * 8 + e] * bf2f((u16)kk[e]);
    }
    scv[j] = sc * 0.125f;
    mx = fmaxf(mx, scv[j]);
  }
  float ssum = 0.f;
  #pragma unroll
  for (int j = 0; j < 16; j++) { scv[j] = __expf(scv[j] - mx); ssum += scv[j]; }
  float inv = 1.f / ssum;
  float o[64];
  #pragma unroll
  for (int d = 0; d < 64; d++) o[d] = 0.f;
  #pragma unroll
  for (int j = 0; j < 16; j++) {
    const short8* vrow = (const short8*)(vb + (h * 16 + j) * 64);
    #pragma unroll
    for (int vv = 0; vv < 8; vv++) {
      short8 vk = vrow[vv];
      #pragma unroll
      for (int e = 0; e < 8; e++) o[vv * 8 + e] += scv[j] * bf2f((u16)vk[e]);
    }
  }
  u16* op = AO + ((size_t)(bl * 16 + t)) * 1024 + h * 64;
  #pragma unroll
  for (int d = 0; d < 64; d++) op[d] = f2bf(o[d] * inv);
}

// ---------- residual: out = base + g[b,d] * P (optional (b,l,t)->(b,t,l) gather of P) ----------
__global__ void resid_kernel(const float* __restrict__ base, const float* __restrict__ P,
                             const float* __restrict__ mods, int gidx,
                             float* __restrict__ out, int transpose) {
  int e = blockIdx.x * 256 + threadIdx.x;
  int row = e >> 10, d = e & 1023;
  int b = row >> 12;
  float g = mods[(size_t)b * 9216 + (size_t)gidx * 1024 + d];
  float p;
  if (transpose) {
    int rem = row & 4095; int t = rem >> 8, l = rem & 255;
    size_t mp = ((size_t)(b << 12)) + (l << 4) + t;
    p = P[(mp << 10) + d];
  } else p = P[e];
  out[e] = base[e] + g * p;
}

// =====================================================================
extern "C" void kernel_launch(void* const* d_in, const int* in_sizes, int n_in,
                              void* d_out, int out_size, void* d_ws, size_t ws_size,
                              hipStream_t stream) {
  const float* x        = (const float*)d_in[0];
  const float* c        = (const float*)d_in[1];
  const float* cos_s    = (const float*)d_in[2];
  const float* sin_s    = (const float*)d_in[3];
  const float* cos_t    = (const float*)d_in[4];
  const float* sin_t    = (const float*)d_in[5];
  const float* norm1w   = (const float*)d_in[6];
  const float* norm2w   = (const float*)d_in[7];
  const float* norm3w   = (const float*)d_in[8];
  const float* qkv_s_w  = (const float*)d_in[9];
  const float* qkv_s_b  = (const float*)d_in[10];
  const float* qn_s_w   = (const float*)d_in[11];
  const float* kn_s_w   = (const float*)d_in[12];
  const float* proj_s_w = (const float*)d_in[13];
  const float* proj_s_b = (const float*)d_in[14];
  const float* qkv_t_w  = (const float*)d_in[15];
  const float* qkv_t_b  = (const float*)d_in[16];
  const float* qn_t_w   = (const float*)d_in[17];
  const float* kn_t_w   = (const float*)d_in[18];
  const float* proj_t_w = (const float*)d_in[19];
  const float* proj_t_b = (const float*)d_in[20];
  const float* w12_w    = (const float*)d_in[21];
  const float* w12_b    = (const float*)d_in[22];
  const float* w3_w     = (const float*)d_in[23];
  const float* w3_b     = (const float*)d_in[24];
  const float* ada_w    = (const float*)d_in[25];
  const float* ada_b    = (const float*)d_in[26];
  float* out = (float*)d_out;

  // ---- workspace layout: ~112.6 MiB (round-3 proven) ----
  char* wsp = (char*)d_ws;
  size_t off = 0;
  auto alloc = [&](size_t bytes) { size_t p = off; off += (bytes + 255) & ~(size_t)255; return p; };
  float* modsb = (float*)(wsp + alloc(2 * 9216 * 4));
  u16*   BIG   = (u16*)  (wsp + alloc((size_t)8192 * 3072 * 2));  // QKV (st1,2) / Hb 8192x2816 (st3)
  char*  XnP   = (char*) (wsp + alloc((size_t)8192 * 1024 * 4));  // Xn bf16 <-> P fp32
  u16*   AO    = (u16*)  (wsp + alloc((size_t)8192 * 1024 * 2));
  u16*   Wq    = (u16*)  (wsp + alloc((size_t)3072 * 1024 * 2));
  u16*   Wp    = (u16*)  (wsp + alloc((size_t)2816 * 1024 * 2));
  u16*   W3b   = (u16*)  (wsp + alloc((size_t)1024 * 2816 * 2));
  u16* W1p = Wq;
  u16* W2p = Wp;
  u16* Xn  = (u16*)XnP;
  float* P = (float*)XnP;
  float* Xcur = out;   // residual stream lives in d_out

  dim3 blk(256);
  int tot;
  mods_kernel<<<2304, blk, 0, stream>>>(c, ada_w, ada_b, modsb);

  // ---- stage 1: spatial attention ----
  tot = 3072 * 1024; cvt_pad_kernel<<<(tot + 255) / 256, blk, 0, stream>>>(qkv_s_w, Wq, 1024, 3072, 1024, 0, tot);
  tot = 1024 * 1024; cvt_pad_kernel<<<(tot + 255) / 256, blk, 0, stream>>>(proj_s_w, Wp, 1024, 1024, 1024, 0, tot);
  norm_mod_kernel<<<8192, blk, 0, stream>>>(x, Xn, norm1w, modsb, 0, 0);
  gemm_bt<1><<<dim3(24, 64), blk, 0, stream>>>(Xn, Wq, qkv_s_b, BIG, 3072, 1024, 3072);
  attn_s_mfma<<<dim3(512, 2), blk, 0, stream>>>(BIG, qn_s_w, kn_s_w, cos_s, sin_s, AO);
  gemm_bt<0><<<dim3(8, 64), blk, 0, stream>>>(AO, Wp, proj_s_b, P, 1024, 1024, 1024);
  resid_kernel<<<32768, blk, 0, stream>>>(x, P, modsb, 2, Xcur, 0);

  // ---- stage 2: temporal attention (rows in (b,l,t) order) ----
  tot = 3072 * 1024; cvt_pad_kernel<<<(tot + 255) / 256, blk, 0, stream>>>(qkv_t_w, Wq, 1024, 3072, 1024, 0, tot);
  tot = 1024 * 1024; cvt_pad_kernel<<<(tot + 255) / 256, blk, 0, stream>>>(proj_t_w, Wp, 1024, 1024, 1024, 0, tot);
  norm_mod_kernel<<<8192, blk, 0, stream>>>(Xcur, Xn, norm2w, modsb, 3, 1);
  gemm_bt<1><<<dim3(24, 64), blk, 0, stream>>>(Xn, Wq, qkv_t_b, BIG, 3072, 1024, 3072);
  attn_t_kernel<<<512, blk, 0, stream>>>(BIG, qn_t_w, kn_t_w, cos_t, sin_t, AO);
  gemm_bt<0><<<dim3(8, 64), blk, 0, stream>>>(AO, Wp, proj_t_b, P, 1024, 1024, 1024);
  resid_kernel<<<32768, blk, 0, stream>>>(Xcur, P, modsb, 5, Xcur, 1);

  // ---- stage 3: SwiGLU MLP (HFF 2730 padded to 2816) ----
  tot = 2816 * 1024; cvt_pad_kernel<<<(tot + 255) / 256, blk, 0, stream>>>(w12_w, W1p, 1024, 2730, 1024, 0, tot);
  tot = 2816 * 1024; cvt_pad_kernel<<<(tot + 255) / 256, blk, 0, stream>>>(w12_w, W2p, 1024, 2730, 1024, 2730, tot);
  tot = 1024 * 2816; cvt_pad_kernel<<<(tot + 255) / 256, blk, 0, stream>>>(w3_w, W3b, 2816, 1024, 2730, 0, tot);
  norm_mod_kernel<<<8192, blk, 0, stream>>>(Xcur, Xn, norm3w, modsb, 6, 0);
  gemm_w12_swiglu<<<dim3(22, 64), blk, 0, stream>>>(Xn, W1p, W2p, w12_b, BIG);
  gemm_bt<0><<<dim3(8, 64), blk, 0, stream>>>(BIG, W3b, w3_b, P, 1024, 2816, 1024);
  resid_kernel<<<32768, blk, 0, stream>>>(Xcur, P, modsb, 8, out, 0);
}